// Round 1
// baseline (939.438 us; speedup 1.0000x reference)
//
#include <hip/hip_runtime.h>

#define BB 256
#define TT 2048
#define FF 64
#define HH 32
#define G4 128

__device__ __forceinline__ float fast_rcp(float x){
#if __has_builtin(__builtin_amdgcn_rcpf)
  return __builtin_amdgcn_rcpf(x);
#else
  return 1.0f/x;
#endif
}
__device__ __forceinline__ float sigf(float x){ return fast_rcp(1.0f + __expf(-x)); }
__device__ __forceinline__ float tanhf2(float x){ return 1.0f - 2.0f*fast_rcp(1.0f + __expf(2.0f*x)); }

// Phase 1: xg[m][c] = x[m_row] @ Wx + b, m = bidx*ct + tt over the current T-chunk.
__global__ __launch_bounds__(256) void lstm_gemm(const float* __restrict__ x,
    const float* __restrict__ Wx, const float* __restrict__ bias,
    float* __restrict__ xg, int t0, int ct)
{
  __shared__ float sW[FF*G4];     // 32 KB
  __shared__ float sB[G4];
  __shared__ float sX[16*68];     // 16 rows, stride 68 to dodge bank conflicts on broadcast
  int tid = threadIdx.x;
  {
    const float4* Wx4 = (const float4*)Wx;
    float4* sW4 = (float4*)sW;
#pragma unroll
    for (int q=0;q<8;q++) sW4[q*256+tid] = Wx4[q*256+tid];
    if (tid < 32) ((float4*)sB)[tid] = ((const float4*)bias)[tid];
  }
  int g = tid >> 4, i = tid & 15;
  long total = (long)BB*ct;
  long m = (long)blockIdx.x*16 + g;
  int bidx = (int)(m / ct);
  int tt   = (int)(m - (long)bidx*ct);
  float4 xv = make_float4(0.f,0.f,0.f,0.f);
  if (m < total) xv = ((const float4*)(x + ((size_t)bidx*TT + t0 + tt)*FF))[i];
  sX[g*68 + i*4+0] = xv.x;
  sX[g*68 + i*4+1] = xv.y;
  sX[g*68 + i*4+2] = xv.z;
  sX[g*68 + i*4+3] = xv.w;
  __syncthreads();
  int col0 = i*8;
  float acc[8];
#pragma unroll
  for (int q=0;q<4;q++){ acc[q]=sB[col0+q]; acc[4+q]=sB[col0+4+q]; }
#pragma unroll
  for (int k=0;k<FF;k++){
    float xk = sX[g*68+k];
    float4 w0 = *(const float4*)&sW[k*G4+col0];
    float4 w1 = *(const float4*)&sW[k*G4+col0+4];
    acc[0]=fmaf(xk,w0.x,acc[0]); acc[1]=fmaf(xk,w0.y,acc[1]);
    acc[2]=fmaf(xk,w0.z,acc[2]); acc[3]=fmaf(xk,w0.w,acc[3]);
    acc[4]=fmaf(xk,w1.x,acc[4]); acc[5]=fmaf(xk,w1.y,acc[5]);
    acc[6]=fmaf(xk,w1.z,acc[6]); acc[7]=fmaf(xk,w1.w,acc[7]);
  }
  if (m < total){
    float* o = xg + (size_t)m*G4 + col0;
    *(float4*)o     = make_float4(acc[0],acc[1],acc[2],acc[3]);
    *(float4*)(o+4) = make_float4(acc[4],acc[5],acc[6],acc[7]);
  }
}

// Phase 2: sequential LSTM scan, one wave (64 lanes) per batch row.
// Lane l owns gate columns l and l+64: l<32 -> (i_l, g_l); l>=32 -> (f_{l-32}, o_{l-32}).
__global__ __launch_bounds__(64) void lstm_scan(const float* __restrict__ xg,
    const float* __restrict__ Wh, float* __restrict__ ys,
    float* __restrict__ state, int t0, int ct)
{
  int r = blockIdx.x;
  int l = threadIdx.x;
  int j = l & 31;
  __shared__ __align__(16) float hbuf[HH];
  float wh0[HH], wh1[HH];
#pragma unroll
  for (int k=0;k<HH;k++){ wh0[k]=Wh[k*G4+l]; wh1[k]=Wh[k*G4+64+l]; }
  float hv[HH]; float c; float h = 0.f;
  if (t0 == 0){
    c = 0.f;
#pragma unroll
    for (int k=0;k<HH;k++) hv[k]=0.f;
  } else {
    c = state[r*HH + j];
    const float4* hp = (const float4*)(state + BB*HH + r*HH);
#pragma unroll
    for (int q=0;q<8;q++){ float4 v=hp[q]; hv[4*q]=v.x; hv[4*q+1]=v.y; hv[4*q+2]=v.z; hv[4*q+3]=v.w; }
  }
  const float* xp = xg + (size_t)r*ct*G4;
  float* yp = ys + ((size_t)r*TT + t0)*HH;
  float cur0[4],cur1[4],nxt0[4],nxt1[4];
#pragma unroll
  for (int u=0;u<4;u++){ int t_ = (u<ct)?u:(ct-1); cur0[u]=xp[t_*G4+l]; cur1[u]=xp[t_*G4+64+l]; }
  for (int tb=0; tb<ct; tb+=4){
#pragma unroll
    for (int u=0;u<4;u++){
      int t_ = tb+4+u; if (t_>=ct) t_=ct-1;
      nxt0[u]=xp[(size_t)t_*G4+l]; nxt1[u]=xp[(size_t)t_*G4+64+l];
    }
#pragma unroll
    for (int u=0;u<4;u++){
      if (tb+u < ct){
        float acc0=cur0[u], acc1=cur1[u];
#pragma unroll
        for (int k=0;k<HH;k++){ acc0=fmaf(hv[k],wh0[k],acc0); acc1=fmaf(hv[k],wh1[k],acc1); }
        float p0=__shfl_xor(acc0,32,64), p1=__shfl_xor(acc1,32,64);
        float gi,gf,gg,go;
        if (l<32){ gi=acc0; gg=acc1; gf=p0; go=p1; }
        else     { gi=p0;  gg=p1;  gf=acc0; go=acc1; }
        c = sigf(gf)*c + sigf(gi)*tanhf2(gg);
        h = sigf(go)*tanhf2(c);
        if (l<32) yp[(size_t)(tb+u)*HH + l] = h;
        else      hbuf[j] = h;
        __syncthreads();   // single wave: orders ds_write -> ds_read, cheap
#pragma unroll
        for (int q=0;q<8;q++){
          float4 v=*(const float4*)&hbuf[4*q];
          hv[4*q]=v.x; hv[4*q+1]=v.y; hv[4*q+2]=v.z; hv[4*q+3]=v.w;
        }
      }
    }
#pragma unroll
    for (int u=0;u<4;u++){ cur0[u]=nxt0[u]; cur1[u]=nxt1[u]; }
  }
  if (l<32) state[r*HH+l] = c;
  else      state[BB*HH + r*HH + j] = h;
}

extern "C" void kernel_launch(void* const* d_in, const int* in_sizes, int n_in,
                              void* d_out, int out_size, void* d_ws, size_t ws_size,
                              hipStream_t stream)
{
  const float* x  = (const float*)d_in[0];
  const float* Wx = (const float*)d_in[1];
  const float* Wh = (const float*)d_in[2];
  const float* b  = (const float*)d_in[3];
  float* ys = (float*)d_out;
  char* ws = (char*)d_ws;
  float* state = (float*)ws;                 // c: BB*HH floats, h: BB*HH floats (64 KB)
  float* xg = (float*)(ws + 65536);
  size_t per_step = (size_t)BB * G4 * sizeof(float);   // 131072 B per timestep of xg
  size_t avail = ws_size > 65536 ? ws_size - 65536 : 0;
  long ctl = (long)(avail / per_step);
  int CT = (ctl >= TT) ? TT : (int)ctl;
  if (CT < 1) CT = 1;
  for (int t0 = 0; t0 < TT; t0 += CT){
    int ct = (TT - t0 < CT) ? (TT - t0) : CT;
    int wgs = (BB*ct + 15)/16;
    lstm_gemm<<<dim3(wgs), dim3(256), 0, stream>>>(x, Wx, b, xg, t0, ct);
    lstm_scan<<<dim3(256), dim3(64), 0, stream>>>(xg, Wh, ys, state, t0, ct);
  }
}

// Round 2
// 698.055 us; speedup vs baseline: 1.3458x; 1.3458x over previous
//
#include <hip/hip_runtime.h>

#define BB 256
#define TT 2048
#define FF 64
#define HH 32
#define G4 128

typedef float f32x2 __attribute__((ext_vector_type(2)));
typedef float f32x4 __attribute__((ext_vector_type(4)));

__device__ __forceinline__ float fast_rcp(float x){
#if __has_builtin(__builtin_amdgcn_rcpf)
  return __builtin_amdgcn_rcpf(x);
#else
  return 1.0f/x;
#endif
}

// packed fp32 FMA: acc += a*b (elementwise on 2 floats), one VALU instruction
#define PKFMA_VV(acc, a, b) asm("v_pk_fma_f32 %0, %1, %2, %0" : "+v"(acc) : "v"(a), "v"(b))
#define PKFMA_SV(acc, a, b) asm("v_pk_fma_f32 %0, %1, %2, %0" : "+v"(acc) : "s"(a), "v"(b))

// ---------------- Phase 1: xg = x @ Wx + b ----------------
// block: 256 threads, tile 64 rows x 128 cols; thread: 8 rows x 4 strided cols.
__global__ __launch_bounds__(256) void lstm_gemm(const float* __restrict__ x,
    const float* __restrict__ Wx, const float* __restrict__ bias,
    float* __restrict__ xg, int t0, int ct)
{
  __shared__ float sW[FF*G4];     // 32 KB, row-major [k][c]
  __shared__ float sB[G4];
  __shared__ float sX[64*68];     // 17 KB, row-major [r][k], pad 68
  int tid = threadIdx.x;
  {
    const float4* Wx4 = (const float4*)Wx;
    float4* sW4 = (float4*)sW;
#pragma unroll
    for (int q=0;q<8;q++) sW4[q*256+tid] = Wx4[q*256+tid];
    if (tid < 32) ((float4*)sB)[tid] = ((const float4*)bias)[tid];
  }
  long total = (long)BB*ct;
  long m0 = (long)blockIdx.x * 64;
#pragma unroll
  for (int s=0;s<4;s++){
    int idx = tid + s*256;          // 0..1023 -> 64 rows x 16 float4
    int row = idx >> 4, q = idx & 15;
    long gm = m0 + row;
    float4 v = make_float4(0.f,0.f,0.f,0.f);
    if (gm < total){
      int bidx = (int)((unsigned long)gm / (unsigned)ct);
      int tt   = (int)(gm - (long)bidx*ct);
      v = ((const float4*)(x + ((size_t)bidx*TT + t0 + tt)*FF))[q];
    }
    *(float4*)&sX[row*68 + q*4] = v;
  }
  __syncthreads();
  int rg = tid >> 5;                // 0..7 -> rows r0..r0+7
  int cg = tid & 31;                // 0..31 -> cols cg, cg+32, cg+64, cg+96
  int r0 = rg*8;
  f32x2 acc[8][4];
#pragma unroll
  for (int r=0;r<8;r++)
#pragma unroll
    for (int c=0;c<4;c++) acc[r][c] = (f32x2){0.f,0.f};
#pragma unroll 8
  for (int kp=0; kp<32; kp++){
    int k = kp*2;
    f32x2 xv[8];
#pragma unroll
    for (int r=0;r<8;r++) xv[r] = *(const f32x2*)&sX[(r0+r)*68 + k];
    f32x2 wv[4];
#pragma unroll
    for (int c=0;c<4;c++){
      f32x2 w; w.x = sW[k*G4 + cg + 32*c]; w.y = sW[(k+1)*G4 + cg + 32*c];
      wv[c] = w;
    }
#pragma unroll
    for (int r=0;r<8;r++)
#pragma unroll
      for (int c=0;c<4;c++) PKFMA_VV(acc[r][c], xv[r], wv[c]);
  }
#pragma unroll
  for (int r=0;r<8;r++){
    long gm = m0 + r0 + r;
    if (gm < total){
      float* o = xg + (size_t)gm*G4;
#pragma unroll
      for (int c=0;c<4;c++)
        o[cg + 32*c] = acc[r][c].x + acc[r][c].y + sB[cg + 32*c];
    }
  }
}

// ---------------- Phase 2: sequential scan ----------------
// One wave per batch row. Lane l: j=l&31, half=l>>5, base=j+half*64.
// acc0 = gate col base (lower: i_j, upper: g_j); acc1 = col base+32 (lower: f_j, upper: o_j).
__global__ __launch_bounds__(64) void lstm_scan(const float* __restrict__ xg,
    const float* __restrict__ Wh, float* __restrict__ ys,
    float* __restrict__ state, int t0, int ct)
{
  int r = blockIdx.x;
  int l = threadIdx.x;
  int j = l & 31;
  int half = l >> 5;
  int base = j + half*64;

  // Wh columns as k-pair f32x2: wp[kk] = {Wh[2kk][col], Wh[2kk+1][col]}
  f32x2 wp0[16], wp1[16];
#pragma unroll
  for (int kk=0;kk<16;kk++){
    f32x2 a; a.x = Wh[(2*kk)*G4 + base];      a.y = Wh[(2*kk+1)*G4 + base];      wp0[kk]=a;
    f32x2 b_; b_.x = Wh[(2*kk)*G4 + base+32]; b_.y = Wh[(2*kk+1)*G4 + base+32]; wp1[kk]=b_;
  }
  // unified activation: t = A*rcp(1+exp(M*x)) + B   (sig: M=-1,A=1,B=0; tanh: M=2,A=-2,B=1)
  float M0 = half ? 2.f : -1.f;
  float A0 = half ? -2.f : 1.f;
  float B0 = half ? 1.f : 0.f;

  float cc, hcur;
  if (t0 == 0){ cc = 0.f; hcur = 0.f; }
  else {
    cc   = state[r*HH + j];
    hcur = state[BB*HH + r*HH + j];
  }

  const float* xp = xg + (size_t)r*ct*G4;
  float* yp = ys + ((size_t)r*TT + t0)*HH;

  float px0[8], px1[8];
#pragma unroll
  for (int u=0;u<8;u++){
    int t_ = (u < ct) ? u : (ct-1);
    px0[u] = xp[(size_t)t_*G4 + base];
    px1[u] = xp[(size_t)t_*G4 + base + 32];
  }

  auto STEP = [&](float xv0, float xv1, int t){
    // broadcast h (lanes 0..31 hold valid h) into SGPR pairs
    f32x2 hp[16];
#pragma unroll
    for (int kk=0;kk<16;kk++){
      f32x2 p;
      p.x = __int_as_float(__builtin_amdgcn_readlane(__float_as_int(hcur), 2*kk));
      p.y = __int_as_float(__builtin_amdgcn_readlane(__float_as_int(hcur), 2*kk+1));
      hp[kk] = p;
    }
    f32x2 a0; a0.x = xv0; a0.y = 0.f;
    f32x2 a1; a1.x = xv1; a1.y = 0.f;
#pragma unroll
    for (int kk=0;kk<16;kk++){
      PKFMA_SV(a0, hp[kk], wp0[kk]);
      PKFMA_SV(a1, hp[kk], wp1[kk]);
    }
    float g0 = a0.x + a0.y;
    float g1 = a1.x + a1.y;
    float t0v = fmaf(A0, fast_rcp(1.f + __expf(M0*g0)), B0);  // lower: sig(i), upper: tanh(g)
    float t1v = fast_rcp(1.f + __expf(-g1));                  // lower: sig(f), upper: sig(o)
    float tg = __shfl_xor(t0v, 32);                           // lower receives tanh(g)
    float so = __shfl_xor(t1v, 32);                           // lower receives sig(o)
    cc = fmaf(t1v, cc, t0v*tg);                               // valid in lower lanes
    float tc = fmaf(-2.f, fast_rcp(1.f + __expf(2.f*cc)), 1.f);
    hcur = so * tc;                                           // valid in lower lanes
    if (half == 0) yp[(size_t)t*HH + j] = hcur;
  };

  int tb = 0;
  for (; tb + 8 <= ct; tb += 8){
#pragma unroll
    for (int u=0;u<8;u++){
      int t = tb + u;
      float xv0 = px0[u], xv1 = px1[u];
      int tn = t + 8; if (tn > ct-1) tn = ct-1;
      px0[u] = xp[(size_t)tn*G4 + base];
      px1[u] = xp[(size_t)tn*G4 + base + 32];
      STEP(xv0, xv1, t);
    }
  }
#pragma unroll
  for (int u=0;u<8;u++){
    int t = tb + u;
    if (t < ct) STEP(px0[u], px1[u], t);
  }

  if (half == 0){
    state[r*HH + j] = cc;
    state[BB*HH + r*HH + j] = hcur;
  }
}

extern "C" void kernel_launch(void* const* d_in, const int* in_sizes, int n_in,
                              void* d_out, int out_size, void* d_ws, size_t ws_size,
                              hipStream_t stream)
{
  const float* x  = (const float*)d_in[0];
  const float* Wx = (const float*)d_in[1];
  const float* Wh = (const float*)d_in[2];
  const float* b  = (const float*)d_in[3];
  float* ys = (float*)d_out;
  char* ws = (char*)d_ws;
  float* state = (float*)ws;                 // c: BB*HH, h: BB*HH (64 KB)
  float* xg = (float*)(ws + 65536);
  size_t per_step = (size_t)BB * G4 * sizeof(float);
  size_t avail = ws_size > 65536 ? ws_size - 65536 : 0;
  long ctl = (long)(avail / per_step);
  int CT = (ctl >= TT) ? TT : (int)ctl;
  if (CT < 1) CT = 1;
  for (int t0 = 0; t0 < TT; t0 += CT){
    int ct = (TT - t0 < CT) ? (TT - t0) : CT;
    int wgs = (int)(((long)BB*ct + 63)/64);
    lstm_gemm<<<dim3(wgs), dim3(256), 0, stream>>>(x, Wx, b, xg, t0, ct);
    lstm_scan<<<dim3(256), dim3(64), 0, stream>>>(xg, Wh, ys, state, t0, ct);
  }
}